// Round 1
// baseline (180.270 us; speedup 1.0000x reference)
//
#include <hip/hip_runtime.h>

#define N_NODES 10000

typedef unsigned int uint;
typedef unsigned short ushort;
typedef __attribute__((ext_vector_type(8))) short bf16x8;
typedef __attribute__((ext_vector_type(4))) float f32x4;

__device__ __forceinline__ ushort f2bf(float f) {
    uint b = __float_as_uint(f);
    b += 0x7fffu + ((b >> 16) & 1u);
    return (ushort)(b >> 16);
}

// ---------------- fused prologue: cast x, transpose-cast weights, zero cnt ----------------
// blocks [0, CAST_B)                : xb = bf16(x), float4/thread
// blocks [CAST_B, CAST_B+TCAST_B)   : W1T/W2T transpose-cast
// blocks [CAST_B+TCAST_B, ...)      : cnt = 0
#define CAST_B 1250   // N_NODES*128/4 / 256
#define TCAST_B 512   // 2*65536 / 256
#define ZERO_B 10     // ceil(N_NODES/4 / 256)

__global__ __launch_bounds__(256) void prep_kernel(const float* __restrict__ x,
                                                   const float* __restrict__ W1l,
                                                   const float* __restrict__ W1r,
                                                   const float* __restrict__ W2l,
                                                   const float* __restrict__ W2r,
                                                   ushort* __restrict__ xb,
                                                   ushort* __restrict__ W1T,
                                                   ushort* __restrict__ W2T,
                                                   int* __restrict__ cnt) {
    int b = blockIdx.x;
    int t = threadIdx.x;
    if (b < CAST_B) {
        int i = b * 256 + t;
        float4 v = ((const float4*)x)[i];
        ushort4 o;
        o.x = f2bf(v.x); o.y = f2bf(v.y); o.z = f2bf(v.z); o.w = f2bf(v.w);
        ((ushort4*)xb)[i] = o;
    } else if (b < CAST_B + TCAST_B) {
        int id = (b - CAST_B) * 256 + t;    // 0..131071
        int z = id >> 16;
        int k = (id >> 8) & 255;
        int c = id & 255;
        if (z == 0) {
            // W1T[c][k] = k<128 ? W1l[k][c] : W1r[k-128][c]
            float v = (k < 128) ? W1l[k * 256 + c] : W1r[(k - 128) * 256 + c];
            W1T[c * 256 + k] = f2bf(v);
        } else {
            // W2T[c][k] = c<128 ? W2l[k][c] : W2r[k][c-128]
            float v = (c < 128) ? W2l[k * 128 + c] : W2r[k * 128 + (c - 128)];
            W2T[c * 256 + k] = f2bf(v);
        }
    } else {
        int i = (b - CAST_B - TCAST_B) * 256 + t;
        if (i < (N_NODES + 3) / 4) ((int4*)cnt)[i] = make_int4(0, 0, 0, 0);
    }
}

// ---------------- CSR build: count -> scan -> scatter ----------------

__global__ __launch_bounds__(256) void count_kernel(const int* __restrict__ dst, int E,
                                                    int* __restrict__ cnt) {
    int g = blockIdx.x * 256 + threadIdx.x;
    int e = g * 4;
    if (e + 3 < E) {
        int4 d = *(const int4*)&dst[e];
        atomicAdd(&cnt[d.x], 1);
        atomicAdd(&cnt[d.y], 1);
        atomicAdd(&cnt[d.z], 1);
        atomicAdd(&cnt[d.w], 1);
    } else {
        for (; e < E; ++e) atomicAdd(&cnt[dst[e]], 1);
    }
}

// single-block shuffle scan: cnt[N] -> row_ptr[N+1], cur[N] = row_ptr[0..N-1]
__global__ __launch_bounds__(1024) void scan_kernel(const int* __restrict__ cnt,
                                                    int* __restrict__ row_ptr,
                                                    int* __restrict__ cur) {
    __shared__ int wsum[16];
    int t = threadIdx.x;
    int base = t * 10;
    int v[10];
    int s = 0;
#pragma unroll
    for (int j = 0; j < 10; ++j) {
        int idx = base + j;
        int c = (idx < N_NODES) ? cnt[idx] : 0;
        s += c;
        v[j] = s;
    }
    int lane = t & 63;
    int incl = s;
#pragma unroll
    for (int off = 1; off < 64; off <<= 1) {
        int y = __shfl_up(incl, off);
        if (lane >= off) incl += y;
    }
    int wid = t >> 6;
    if (lane == 63) wsum[wid] = incl;
    __syncthreads();
    int wbase = 0;
#pragma unroll
    for (int w = 0; w < 16; ++w)
        if (w < wid) wbase += wsum[w];
    int texcl = wbase + incl - s;
    if (t == 0) row_ptr[0] = 0;
    int run = texcl;
#pragma unroll
    for (int j = 0; j < 10; ++j) {
        int idx = base + j;
        if (idx < N_NODES) {
            cur[idx] = run;
            row_ptr[idx + 1] = texcl + v[j];
        }
        run = texcl + v[j];
    }
}

// scatter with atomic rank allocation
__global__ __launch_bounds__(256) void scatter_kernel(const int* __restrict__ src,
                                                      const int* __restrict__ dst,
                                                      int* __restrict__ cur, int E,
                                                      ushort* __restrict__ csr) {
    int g = blockIdx.x * 256 + threadIdx.x;
    int e = g * 4;
    if (e + 3 < E) {
        int4 d = *(const int4*)&dst[e];
        int4 s = *(const int4*)&src[e];
        int p0 = atomicAdd(&cur[d.x], 1);
        int p1 = atomicAdd(&cur[d.y], 1);
        int p2 = atomicAdd(&cur[d.z], 1);
        int p3 = atomicAdd(&cur[d.w], 1);
        csr[p0] = (ushort)s.x;
        csr[p1] = (ushort)s.y;
        csr[p2] = (ushort)s.z;
        csr[p3] = (ushort)s.w;
    } else {
        for (; e < E; ++e) {
            int p = atomicAdd(&cur[dst[e]], 1);
            csr[p] = (ushort)src[e];
        }
    }
}

// ---------------- Aggregation (gather mean), bf16 feat, 128 channels ----------------
// MODE 0: write packed bf16 mean -> outb ; MODE 1: out f32 += mean
template <int MODE>
__global__ __launch_bounds__(256) void agg_kernel(const ushort* __restrict__ feat,
                                                  const int* __restrict__ row_ptr,
                                                  const ushort* __restrict__ csr,
                                                  uint* __restrict__ outb,
                                                  float* __restrict__ out) {
    int wave = threadIdx.x >> 6;
    int lane = threadIdx.x & 63;
    int n = blockIdx.x * 4 + wave;
    if (n >= N_NODES) return;
    int beg = row_ptr[n], end = row_ptr[n + 1];
    const uint* f = (const uint*)feat;
    float ax0 = 0, ay0 = 0, ax1 = 0, ay1 = 0, ax2 = 0, ay2 = 0, ax3 = 0, ay3 = 0;
    int i = beg;
    for (; i + 4 <= end; i += 4) {
        int s0 = csr[i + 0];
        int s1 = csr[i + 1];
        int s2 = csr[i + 2];
        int s3 = csr[i + 3];
        uint u0 = f[s0 * 64 + lane];
        uint u1 = f[s1 * 64 + lane];
        uint u2 = f[s2 * 64 + lane];
        uint u3 = f[s3 * 64 + lane];
        ax0 += __uint_as_float(u0 << 16); ay0 += __uint_as_float(u0 & 0xffff0000u);
        ax1 += __uint_as_float(u1 << 16); ay1 += __uint_as_float(u1 & 0xffff0000u);
        ax2 += __uint_as_float(u2 << 16); ay2 += __uint_as_float(u2 & 0xffff0000u);
        ax3 += __uint_as_float(u3 << 16); ay3 += __uint_as_float(u3 & 0xffff0000u);
    }
    for (; i < end; ++i) {
        int s = csr[i];
        uint u = f[s * 64 + lane];
        ax0 += __uint_as_float(u << 16); ay0 += __uint_as_float(u & 0xffff0000u);
    }
    float deg = (float)(end - beg);
    float inv = deg > 0.f ? 1.0f / deg : 0.0f;
    float sx = ((ax0 + ax1) + (ax2 + ax3)) * inv;
    float sy = ((ay0 + ay1) + (ay2 + ay3)) * inv;
    if (MODE == 0) {
        outb[n * 64 + lane] = (uint)f2bf(sx) | ((uint)f2bf(sy) << 16);
    } else {
        float2* o = (float2*)&out[n * 128 + lane * 2];
        float2 prev = *o;
        prev.x += sx; prev.y += sy;
        *o = prev;
    }
}

// ---------------- MFMA GEMM 1: hb = relu([mean1|x] @ W1T^T + b1), bf16 out ----------------
__global__ __launch_bounds__(256) void gemm1_mfma(const ushort* __restrict__ m1b,
                                                  const ushort* __restrict__ xb,
                                                  const ushort* __restrict__ W1T,
                                                  const float* __restrict__ b1,
                                                  ushort* __restrict__ hb) {
    int w = threadIdx.x >> 6, lane = threadIdx.x & 63;
    int r0 = blockIdx.x * 64 + w * 16;
    int c0 = blockIdx.y * 64;
    int lr = lane & 15, lg = lane >> 4;
    f32x4 acc[4] = {};
    int row = r0 + lr;
    bool rok = row < N_NODES;
#pragma unroll
    for (int ks = 0; ks < 8; ++ks) {
        int k0 = ks * 32;
        const ushort* Ab = (k0 < 128) ? (m1b + row * 128 + k0) : (xb + row * 128 + (k0 - 128));
        bf16x8 a = {};
        if (rok) a = *(const bf16x8*)(Ab + lg * 8);
#pragma unroll
        for (int cg = 0; cg < 4; ++cg) {
            int col = c0 + cg * 16 + lr;
            bf16x8 b = *(const bf16x8*)(W1T + col * 256 + k0 + lg * 8);
            acc[cg] = __builtin_amdgcn_mfma_f32_16x16x32_bf16(a, b, acc[cg], 0, 0, 0);
        }
    }
#pragma unroll
    for (int cg = 0; cg < 4; ++cg) {
        int col = c0 + cg * 16 + lr;
        float bias = b1[col];
#pragma unroll
        for (int i = 0; i < 4; ++i) {
            int rr = r0 + lg * 4 + i;
            if (rr < N_NODES) {
                float v = acc[cg][i] + bias;
                v = v > 0.f ? v : 0.f;
                hb[rr * 256 + col] = f2bf(v);
            }
        }
    }
}

// ---------------- MFMA GEMM 2: vcols 0-127 -> t=bf16(hb@W2l); 128-255 -> out=hb@W2r+b2 ----------------
__global__ __launch_bounds__(256) void gemm2_mfma(const ushort* __restrict__ hb,
                                                  const ushort* __restrict__ W2T,
                                                  const float* __restrict__ b2,
                                                  ushort* __restrict__ t,
                                                  float* __restrict__ out) {
    int w = threadIdx.x >> 6, lane = threadIdx.x & 63;
    int r0 = blockIdx.x * 64 + w * 16;
    int c0 = blockIdx.y * 64;
    int lr = lane & 15, lg = lane >> 4;
    f32x4 acc[4] = {};
    int row = r0 + lr;
    bool rok = row < N_NODES;
#pragma unroll
    for (int ks = 0; ks < 8; ++ks) {
        int k0 = ks * 32;
        bf16x8 a = {};
        if (rok) a = *(const bf16x8*)(hb + row * 256 + k0 + lg * 8);
#pragma unroll
        for (int cg = 0; cg < 4; ++cg) {
            int col = c0 + cg * 16 + lr;
            bf16x8 b = *(const bf16x8*)(W2T + col * 256 + k0 + lg * 8);
            acc[cg] = __builtin_amdgcn_mfma_f32_16x16x32_bf16(a, b, acc[cg], 0, 0, 0);
        }
    }
#pragma unroll
    for (int cg = 0; cg < 4; ++cg) {
        int col = c0 + cg * 16 + lr;
        if (col < 128) {
#pragma unroll
            for (int i = 0; i < 4; ++i) {
                int rr = r0 + lg * 4 + i;
                if (rr < N_NODES) t[rr * 128 + col] = f2bf(acc[cg][i]);
            }
        } else {
            int oc = col - 128;
            float bias = b2[oc];
#pragma unroll
            for (int i = 0; i < 4; ++i) {
                int rr = r0 + lg * 4 + i;
                if (rr < N_NODES) out[rr * 128 + oc] = acc[cg][i] + bias;
            }
        }
    }
}

// ---------------- launch ----------------

extern "C" void kernel_launch(void* const* d_in, const int* in_sizes, int n_in,
                              void* d_out, int out_size, void* d_ws, size_t ws_size,
                              hipStream_t stream) {
    const float* x   = (const float*)d_in[0];
    const int* edge  = (const int*)d_in[1];
    const float* W1l = (const float*)d_in[2];
    const float* W1r = (const float*)d_in[3];
    const float* b1  = (const float*)d_in[4];
    const float* W2l = (const float*)d_in[5];
    const float* W2r = (const float*)d_in[6];
    const float* b2  = (const float*)d_in[7];
    float* out = (float*)d_out;

    int E = in_sizes[1] / 2;
    const int* src = edge;
    const int* dst = edge + E;

    // workspace layout
    ushort* m1b  = (ushort*)d_ws;                         // [N,128] bf16 mean1 (later aliased by t)
    ushort* hb   = m1b + (size_t)N_NODES * 128;           // [N,256] bf16
    ushort* xb   = hb + (size_t)N_NODES * 256;            // [N,128] bf16
    ushort* W1T  = xb + (size_t)N_NODES * 128;            // [256][256] bf16
    ushort* W2T  = W1T + 256 * 256;                       // [256][256] bf16
    ushort* csr  = W2T + 256 * 256;                       // [E]
    size_t csre  = (size_t)((E + 1) & ~1);                // keep int alignment
    int* cnt     = (int*)(csr + csre);                    // [N]
    int* row_ptr = cnt + N_NODES;                         // [N+1]
    int* cur     = row_ptr + (N_NODES + 1);               // [N]
    ushort* tb   = m1b;                                   // t aliases mean1

    // fused prologue: cast x, tcast weights, zero cnt
    prep_kernel<<<CAST_B + TCAST_B + ZERO_B, 256, 0, stream>>>(x, W1l, W1r, W2l, W2r,
                                                               xb, W1T, W2T, cnt);

    // CSR build: count -> scan -> scatter (global atomics, L2-resident counters)
    int eb = ((E + 3) / 4 + 255) / 256;
    count_kernel<<<eb, 256, 0, stream>>>(dst, E, cnt);
    scan_kernel<<<1, 1024, 0, stream>>>(cnt, row_ptr, cur);
    scatter_kernel<<<eb, 256, 0, stream>>>(src, dst, cur, E, csr);

    // layer 1
    agg_kernel<0><<<(N_NODES + 3) / 4, 256, 0, stream>>>(xb, row_ptr, csr, (uint*)m1b, nullptr);
    dim3 g1((N_NODES + 63) / 64, 4);
    gemm1_mfma<<<g1, 256, 0, stream>>>(m1b, xb, W1T, b1, hb);

    // layer 2 (reordered): t = bf16(h@W2l); out = h@W2r + b2; out += segment_mean(t)
    gemm2_mfma<<<g1, 256, 0, stream>>>(hb, W2T, b2, tb, out);
    agg_kernel<1><<<(N_NODES + 3) / 4, 256, 0, stream>>>(tb, row_ptr, csr, nullptr, out);
}

// Round 2
// 123.296 us; speedup vs baseline: 1.4621x; 1.4621x over previous
//
#include <hip/hip_runtime.h>

#define N_NODES 10000
#define HB 64          // histogram chunks

typedef unsigned int uint;
typedef unsigned short ushort;
typedef __attribute__((ext_vector_type(8))) short bf16x8;
typedef __attribute__((ext_vector_type(4))) float f32x4;

__device__ __forceinline__ ushort f2bf(float f) {
    uint b = __float_as_uint(f);
    b += 0x7fffu + ((b >> 16) & 1u);
    return (ushort)(b >> 16);
}

// ---------------- fused prologue ----------------
// blocks [0, HB)            : per-chunk LDS histogram + local rank (CSR critical path, first)
// blocks [HB, HB+CAST_B)    : xb = bf16(x)
// blocks [HB+CAST_B, ...)   : W1T/W2T transpose-cast
#define CAST_B 1250   // N_NODES*128/4 / 256
#define TCAST_B 512   // 2*65536 / 256

__global__ __launch_bounds__(256) void prep_kernel(const float* __restrict__ x,
                                                   const float* __restrict__ W1l,
                                                   const float* __restrict__ W1r,
                                                   const float* __restrict__ W2l,
                                                   const float* __restrict__ W2r,
                                                   const int* __restrict__ dst, int E, int chunk,
                                                   int* __restrict__ chunk_hist,
                                                   ushort* __restrict__ lrank,
                                                   ushort* __restrict__ xb,
                                                   ushort* __restrict__ W1T,
                                                   ushort* __restrict__ W2T) {
    __shared__ int hist[N_NODES];   // 40 KB -> 4 blocks/CU for all regions (fine, memory-bound)
    int b = blockIdx.x;
    int t = threadIdx.x;
    if (b < HB) {
        for (int i = t; i < N_NODES; i += 256) hist[i] = 0;
        __syncthreads();
        int e0 = b * chunk;
        int e1 = e0 + chunk; if (e1 > E) e1 = E;
        for (int e = e0 + t; e < e1; e += 256) {
            int d = dst[e];
            lrank[e] = (ushort)atomicAdd(&hist[d], 1);
        }
        __syncthreads();
        for (int i = t; i < N_NODES; i += 256) chunk_hist[b * N_NODES + i] = hist[i];
    } else if (b < HB + CAST_B) {
        int i = (b - HB) * 256 + t;
        float4 v = ((const float4*)x)[i];
        ushort4 o;
        o.x = f2bf(v.x); o.y = f2bf(v.y); o.z = f2bf(v.z); o.w = f2bf(v.w);
        ((ushort4*)xb)[i] = o;
    } else {
        int id = (b - HB - CAST_B) * 256 + t;    // 0..131071
        int z = id >> 16;
        int k = (id >> 8) & 255;
        int c = id & 255;
        if (z == 0) {
            // W1T[c][k] = k<128 ? W1l[k][c] : W1r[k-128][c]
            float v = (k < 128) ? W1l[k * 256 + c] : W1r[(k - 128) * 256 + c];
            W1T[c * 256 + k] = f2bf(v);
        } else {
            // W2T[c][k] = c<128 ? W2l[k][c] : W2r[k][c-128]
            float v = (c < 128) ? W2l[k * 128 + c] : W2r[k * 128 + (c - 128)];
            W2T[c * 256 + k] = f2bf(v);
        }
    }
}

// ---------------- CSR build (no global atomics) ----------------

__global__ __launch_bounds__(256) void colsum_kernel(const int* __restrict__ ch,
                                                     int* __restrict__ cnt) {
    int n = blockIdx.x * 256 + threadIdx.x;
    if (n >= N_NODES) return;
    int s = 0;
#pragma unroll 8
    for (int b = 0; b < HB; ++b) s += ch[b * N_NODES + n];
    cnt[n] = s;
}

// single-block shuffle scan: cnt[N] -> row_ptr[N+1]
__global__ __launch_bounds__(1024) void scan_kernel(const int* __restrict__ cnt,
                                                    int* __restrict__ row_ptr) {
    __shared__ int wsum[16];
    int t = threadIdx.x;
    int base = t * 10;
    int v[10];
    int s = 0;
#pragma unroll
    for (int j = 0; j < 10; ++j) {
        int idx = base + j;
        int c = (idx < N_NODES) ? cnt[idx] : 0;
        s += c;
        v[j] = s;
    }
    int lane = t & 63;
    int incl = s;
#pragma unroll
    for (int off = 1; off < 64; off <<= 1) {
        int y = __shfl_up(incl, off);
        if (lane >= off) incl += y;
    }
    int wid = t >> 6;
    if (lane == 63) wsum[wid] = incl;
    __syncthreads();
    int wbase = 0;
#pragma unroll
    for (int w = 0; w < 16; ++w)
        if (w < wid) wbase += wsum[w];
    int texcl = wbase + incl - s;
    if (t == 0) row_ptr[0] = 0;
#pragma unroll
    for (int j = 0; j < 10; ++j) {
        int idx = base + j;
        if (idx < N_NODES) row_ptr[idx + 1] = texcl + v[j];
    }
}

// chunk_hist[b][n] -> starting offset of (chunk b, node n), in place
__global__ __launch_bounds__(256) void offs_kernel(int* __restrict__ ch,
                                                   const int* __restrict__ row_ptr) {
    int n = blockIdx.x * 256 + threadIdx.x;
    if (n >= N_NODES) return;
    int run = row_ptr[n];
#pragma unroll 8
    for (int b = 0; b < HB; ++b) {
        int v = ch[b * N_NODES + n];
        ch[b * N_NODES + n] = run;
        run += v;
    }
}

// atomic-free scatter
__global__ __launch_bounds__(256) void scatter_kernel(const int* __restrict__ src,
                                                      const int* __restrict__ dst,
                                                      const ushort* __restrict__ lrank,
                                                      const int* __restrict__ off,
                                                      int E, int chunk,
                                                      ushort* __restrict__ csr) {
    int g = blockIdx.x * blockDim.x + threadIdx.x;
    int e = g * 4;
    if (e + 3 < E) {
        int b = e / chunk;                    // chunk is multiple of 4, so uniform for the 4-group
        const int* ob = off + b * N_NODES;
        int4 d = *(const int4*)&dst[e];
        int4 s = *(const int4*)&src[e];
        ushort4 r = *(const ushort4*)&lrank[e];
        csr[ob[d.x] + r.x] = (ushort)s.x;
        csr[ob[d.y] + r.y] = (ushort)s.y;
        csr[ob[d.z] + r.z] = (ushort)s.z;
        csr[ob[d.w] + r.w] = (ushort)s.w;
    } else {
        for (; e < E; ++e)
            csr[off[(e / chunk) * N_NODES + dst[e]] + lrank[e]] = (ushort)src[e];
    }
}

// ---------------- Aggregation (gather mean), bf16 feat, 128 channels ----------------
// MODE 0: write packed bf16 mean -> outb ; MODE 1: out f32 += mean
template <int MODE>
__global__ __launch_bounds__(256) void agg_kernel(const ushort* __restrict__ feat,
                                                  const int* __restrict__ row_ptr,
                                                  const ushort* __restrict__ csr,
                                                  uint* __restrict__ outb,
                                                  float* __restrict__ out) {
    int wave = threadIdx.x >> 6;
    int lane = threadIdx.x & 63;
    int n = blockIdx.x * 4 + wave;
    if (n >= N_NODES) return;
    int beg = row_ptr[n], end = row_ptr[n + 1];
    const uint* f = (const uint*)feat;
    float ax0 = 0, ay0 = 0, ax1 = 0, ay1 = 0, ax2 = 0, ay2 = 0, ax3 = 0, ay3 = 0;
    int i = beg;
    for (; i + 4 <= end; i += 4) {
        int s0 = csr[i + 0];
        int s1 = csr[i + 1];
        int s2 = csr[i + 2];
        int s3 = csr[i + 3];
        uint u0 = f[s0 * 64 + lane];
        uint u1 = f[s1 * 64 + lane];
        uint u2 = f[s2 * 64 + lane];
        uint u3 = f[s3 * 64 + lane];
        ax0 += __uint_as_float(u0 << 16); ay0 += __uint_as_float(u0 & 0xffff0000u);
        ax1 += __uint_as_float(u1 << 16); ay1 += __uint_as_float(u1 & 0xffff0000u);
        ax2 += __uint_as_float(u2 << 16); ay2 += __uint_as_float(u2 & 0xffff0000u);
        ax3 += __uint_as_float(u3 << 16); ay3 += __uint_as_float(u3 & 0xffff0000u);
    }
    for (; i < end; ++i) {
        int s = csr[i];
        uint u = f[s * 64 + lane];
        ax0 += __uint_as_float(u << 16); ay0 += __uint_as_float(u & 0xffff0000u);
    }
    float deg = (float)(end - beg);
    float inv = deg > 0.f ? 1.0f / deg : 0.0f;
    float sx = ((ax0 + ax1) + (ax2 + ax3)) * inv;
    float sy = ((ay0 + ay1) + (ay2 + ay3)) * inv;
    if (MODE == 0) {
        outb[n * 64 + lane] = (uint)f2bf(sx) | ((uint)f2bf(sy) << 16);
    } else {
        float2* o = (float2*)&out[n * 128 + lane * 2];
        float2 prev = *o;
        prev.x += sx; prev.y += sy;
        *o = prev;
    }
}

// ---------------- MFMA GEMM 1: hb = relu([mean1|x] @ W1T^T + b1), bf16 out ----------------
__global__ __launch_bounds__(256) void gemm1_mfma(const ushort* __restrict__ m1b,
                                                  const ushort* __restrict__ xb,
                                                  const ushort* __restrict__ W1T,
                                                  const float* __restrict__ b1,
                                                  ushort* __restrict__ hb) {
    int w = threadIdx.x >> 6, lane = threadIdx.x & 63;
    int r0 = blockIdx.x * 64 + w * 16;
    int c0 = blockIdx.y * 64;
    int lr = lane & 15, lg = lane >> 4;
    f32x4 acc[4] = {};
    int row = r0 + lr;
    bool rok = row < N_NODES;
#pragma unroll
    for (int ks = 0; ks < 8; ++ks) {
        int k0 = ks * 32;
        const ushort* Ab = (k0 < 128) ? (m1b + row * 128 + k0) : (xb + row * 128 + (k0 - 128));
        bf16x8 a = {};
        if (rok) a = *(const bf16x8*)(Ab + lg * 8);
#pragma unroll
        for (int cg = 0; cg < 4; ++cg) {
            int col = c0 + cg * 16 + lr;
            bf16x8 b = *(const bf16x8*)(W1T + col * 256 + k0 + lg * 8);
            acc[cg] = __builtin_amdgcn_mfma_f32_16x16x32_bf16(a, b, acc[cg], 0, 0, 0);
        }
    }
#pragma unroll
    for (int cg = 0; cg < 4; ++cg) {
        int col = c0 + cg * 16 + lr;
        float bias = b1[col];
#pragma unroll
        for (int i = 0; i < 4; ++i) {
            int rr = r0 + lg * 4 + i;
            if (rr < N_NODES) {
                float v = acc[cg][i] + bias;
                v = v > 0.f ? v : 0.f;
                hb[rr * 256 + col] = f2bf(v);
            }
        }
    }
}

// ---------------- MFMA GEMM 2: vcols 0-127 -> t=bf16(hb@W2l); 128-255 -> out=hb@W2r+b2 ----------------
__global__ __launch_bounds__(256) void gemm2_mfma(const ushort* __restrict__ hb,
                                                  const ushort* __restrict__ W2T,
                                                  const float* __restrict__ b2,
                                                  ushort* __restrict__ t,
                                                  float* __restrict__ out) {
    int w = threadIdx.x >> 6, lane = threadIdx.x & 63;
    int r0 = blockIdx.x * 64 + w * 16;
    int c0 = blockIdx.y * 64;
    int lr = lane & 15, lg = lane >> 4;
    f32x4 acc[4] = {};
    int row = r0 + lr;
    bool rok = row < N_NODES;
#pragma unroll
    for (int ks = 0; ks < 8; ++ks) {
        int k0 = ks * 32;
        bf16x8 a = {};
        if (rok) a = *(const bf16x8*)(hb + row * 256 + k0 + lg * 8);
#pragma unroll
        for (int cg = 0; cg < 4; ++cg) {
            int col = c0 + cg * 16 + lr;
            bf16x8 b = *(const bf16x8*)(W2T + col * 256 + k0 + lg * 8);
            acc[cg] = __builtin_amdgcn_mfma_f32_16x16x32_bf16(a, b, acc[cg], 0, 0, 0);
        }
    }
#pragma unroll
    for (int cg = 0; cg < 4; ++cg) {
        int col = c0 + cg * 16 + lr;
        if (col < 128) {
#pragma unroll
            for (int i = 0; i < 4; ++i) {
                int rr = r0 + lg * 4 + i;
                if (rr < N_NODES) t[rr * 128 + col] = f2bf(acc[cg][i]);
            }
        } else {
            int oc = col - 128;
            float bias = b2[oc];
#pragma unroll
            for (int i = 0; i < 4; ++i) {
                int rr = r0 + lg * 4 + i;
                if (rr < N_NODES) out[rr * 128 + oc] = acc[cg][i] + bias;
            }
        }
    }
}

// ---------------- launch ----------------

extern "C" void kernel_launch(void* const* d_in, const int* in_sizes, int n_in,
                              void* d_out, int out_size, void* d_ws, size_t ws_size,
                              hipStream_t stream) {
    const float* x   = (const float*)d_in[0];
    const int* edge  = (const int*)d_in[1];
    const float* W1l = (const float*)d_in[2];
    const float* W1r = (const float*)d_in[3];
    const float* b1  = (const float*)d_in[4];
    const float* W2l = (const float*)d_in[5];
    const float* W2r = (const float*)d_in[6];
    const float* b2  = (const float*)d_in[7];
    float* out = (float*)d_out;

    int E = in_sizes[1] / 2;
    const int* src = edge;
    const int* dst = edge + E;
    int chunk = (((E + HB - 1) / HB) + 3) & ~3;   // chunk multiple of 4

    // workspace layout
    ushort* m1b  = (ushort*)d_ws;                         // [N,128] bf16 mean1 (later aliased by t)
    ushort* hb   = m1b + (size_t)N_NODES * 128;           // [N,256] bf16
    ushort* xb   = hb + (size_t)N_NODES * 256;            // [N,128] bf16
    ushort* W1T  = xb + (size_t)N_NODES * 128;            // [256][256] bf16
    ushort* W2T  = W1T + 256 * 256;                       // [256][256] bf16
    ushort* csr  = W2T + 256 * 256;                       // [E]
    ushort* lrank= csr + E;                               // [E]
    int* chist   = (int*)(lrank + E);                     // [HB][N]
    int* row_ptr = chist + HB * N_NODES;                  // [N+1]
    int* cnt     = row_ptr + (N_NODES + 1);               // [N]
    ushort* tb   = m1b;                                   // t aliases mean1

    // fused prologue: hist (first, CSR critical path) + cast x + tcast weights
    prep_kernel<<<HB + CAST_B + TCAST_B, 256, 0, stream>>>(x, W1l, W1r, W2l, W2r,
                                                           dst, E, chunk, chist, lrank,
                                                           xb, W1T, W2T);

    // CSR build (no global atomics)
    colsum_kernel<<<(N_NODES + 255) / 256, 256, 0, stream>>>(chist, cnt);
    scan_kernel<<<1, 1024, 0, stream>>>(cnt, row_ptr);
    offs_kernel<<<(N_NODES + 255) / 256, 256, 0, stream>>>(chist, row_ptr);
    scatter_kernel<<<(E / 4 + 255) / 256, 256, 0, stream>>>(src, dst, lrank, chist, E, chunk, csr);

    // layer 1
    agg_kernel<0><<<(N_NODES + 3) / 4, 256, 0, stream>>>(xb, row_ptr, csr, (uint*)m1b, nullptr);
    dim3 g1((N_NODES + 63) / 64, 4);
    gemm1_mfma<<<g1, 256, 0, stream>>>(m1b, xb, W1T, b1, hb);

    // layer 2 (reordered): t = bf16(h@W2l); out = h@W2r + b2; out += segment_mean(t)
    gemm2_mfma<<<g1, 256, 0, stream>>>(hb, W2T, b2, tb, out);
    agg_kernel<1><<<(N_NODES + 3) / 4, 256, 0, stream>>>(tb, row_ptr, csr, nullptr, out);
}

// Round 3
// 116.200 us; speedup vs baseline: 1.5514x; 1.0611x over previous
//
#include <hip/hip_runtime.h>

#define N_NODES 10000
#define HB 64          // histogram chunks

typedef unsigned int uint;
typedef unsigned short ushort;
typedef __attribute__((ext_vector_type(8))) short bf16x8;
typedef __attribute__((ext_vector_type(4))) float f32x4;

__device__ __forceinline__ ushort f2bf(float f) {
    uint b = __float_as_uint(f);
    b += 0x7fffu + ((b >> 16) & 1u);
    return (ushort)(b >> 16);
}

// ---------------- fused prologue ----------------
// blocks [0, HB)            : per-chunk LDS histogram + local rank (CSR critical path, first)
// blocks [HB, HB+CAST_B)    : xb = bf16(x)   (block HB also zeroes aggv flags)
// blocks [HB+CAST_B, ...)   : W1T/W2T transpose-cast
#define CAST_B 1250   // N_NODES*128/4 / 256
#define TCAST_B 512   // 2*65536 / 256

__global__ __launch_bounds__(256) void prep_kernel(const float* __restrict__ x,
                                                   const float* __restrict__ W1l,
                                                   const float* __restrict__ W1r,
                                                   const float* __restrict__ W2l,
                                                   const float* __restrict__ W2r,
                                                   const int* __restrict__ dst, int E, int chunk,
                                                   int* __restrict__ chunk_hist,
                                                   ushort* __restrict__ lrank,
                                                   ushort* __restrict__ xb,
                                                   ushort* __restrict__ W1T,
                                                   ushort* __restrict__ W2T,
                                                   int* __restrict__ aggv) {
    __shared__ int hist[N_NODES];   // 40 KB
    int b = blockIdx.x;
    int t = threadIdx.x;
    if (b < HB) {
        for (int i = t; i < N_NODES; i += 256) hist[i] = 0;
        __syncthreads();
        int e0 = b * chunk;
        int e1 = e0 + chunk; if (e1 > E) e1 = E;
        for (int e = e0 + t; e < e1; e += 256) {
            int d = dst[e];
            lrank[e] = (ushort)atomicAdd(&hist[d], 1);
        }
        __syncthreads();
        for (int i = t; i < N_NODES; i += 256) chunk_hist[b * N_NODES + i] = hist[i];
    } else if (b < HB + CAST_B) {
        if (b == HB && t < 64) aggv[t] = 0;    // zero lookback flags for csr_mid
        int i = (b - HB) * 256 + t;
        float4 v = ((const float4*)x)[i];
        ushort4 o;
        o.x = f2bf(v.x); o.y = f2bf(v.y); o.z = f2bf(v.z); o.w = f2bf(v.w);
        ((ushort4*)xb)[i] = o;
    } else {
        int id = (b - HB - CAST_B) * 256 + t;    // 0..131071
        int z = id >> 16;
        int k = (id >> 8) & 255;
        int c = id & 255;
        if (z == 0) {
            // W1T[c][k] = k<128 ? W1l[k][c] : W1r[k-128][c]
            float v = (k < 128) ? W1l[k * 256 + c] : W1r[(k - 128) * 256 + c];
            W1T[c * 256 + k] = f2bf(v);
        } else {
            // W2T[c][k] = c<128 ? W2l[k][c] : W2r[k][c-128]
            float v = (c < 128) ? W2l[k * 128 + c] : W2r[k * 128 + (c - 128)];
            W2T[c * 256 + k] = f2bf(v);
        }
    }
}

// ---------------- CSR mid-chain, fused: colsum + scan (decoupled lookback) + offs ----------------
// grid = 40 blocks x 256 threads; thread t of block b owns node n = b*256+t.
// 1) s = sum over chunks of chist[c][n]
// 2) block-wide inclusive scan of s; publish block aggregate (release, device scope)
// 3) spin-read predecessor aggregates (acquire) -> global base; write row_ptr
// 4) offs: rewrite chist[c][n] to running start offsets
__global__ __launch_bounds__(256) void csr_mid_kernel(int* __restrict__ ch,
                                                      int* __restrict__ row_ptr,
                                                      int* __restrict__ aggv) {
    int b = blockIdx.x, t = threadIdx.x;
    int n = b * 256 + t;
    bool ok = n < N_NODES;
    int s = 0;
    if (ok) {
#pragma unroll 8
        for (int c = 0; c < HB; ++c) s += ch[c * N_NODES + n];
    }
    // block-wide inclusive scan
    int lane = t & 63, wid = t >> 6;
    int incl = s;
#pragma unroll
    for (int off = 1; off < 64; off <<= 1) {
        int y = __shfl_up(incl, off);
        if (lane >= off) incl += y;
    }
    __shared__ int wsum[4];
    __shared__ int sbase;
    if (lane == 63) wsum[wid] = incl;
    __syncthreads();
    int tot = wsum[0] + wsum[1] + wsum[2] + wsum[3];
    int wbase = 0;
#pragma unroll
    for (int w = 0; w < 4; ++w)
        if (w < wid) wbase += wsum[w];
    incl += wbase;
    // publish aggregate FIRST (no circular wait), then look back
    if (t == 0)
        __hip_atomic_store(&aggv[b], tot + 1, __ATOMIC_RELEASE, __HIP_MEMORY_SCOPE_AGENT);
    if (t < 64) {
        int v = 0;
        if (t < b) {
            do {
                v = __hip_atomic_load(&aggv[t], __ATOMIC_ACQUIRE, __HIP_MEMORY_SCOPE_AGENT);
            } while (v == 0);
            --v;
        }
#pragma unroll
        for (int m = 1; m < 64; m <<= 1) v += __shfl_xor(v, m);
        if (t == 0) sbase = v;
    }
    __syncthreads();
    int base = sbase;
    if (b == 0 && t == 0) row_ptr[0] = 0;
    if (ok) {
        row_ptr[n + 1] = base + incl;
        int run = base + incl - s;      // exclusive prefix = global start of node n
#pragma unroll 8
        for (int c = 0; c < HB; ++c) {
            int v = ch[c * N_NODES + n];
            ch[c * N_NODES + n] = run;
            run += v;
        }
    }
}

// ---------------- atomic-free scatter ----------------
__global__ __launch_bounds__(256) void scatter_kernel(const int* __restrict__ src,
                                                      const int* __restrict__ dst,
                                                      const ushort* __restrict__ lrank,
                                                      const int* __restrict__ off,
                                                      int E, int chunk,
                                                      ushort* __restrict__ csr) {
    int g = blockIdx.x * blockDim.x + threadIdx.x;
    int e = g * 4;
    if (e + 3 < E) {
        int b = e / chunk;                    // chunk is multiple of 4, so uniform for the 4-group
        const int* ob = off + b * N_NODES;
        int4 d = *(const int4*)&dst[e];
        int4 s = *(const int4*)&src[e];
        ushort4 r = *(const ushort4*)&lrank[e];
        csr[ob[d.x] + r.x] = (ushort)s.x;
        csr[ob[d.y] + r.y] = (ushort)s.y;
        csr[ob[d.z] + r.z] = (ushort)s.z;
        csr[ob[d.w] + r.w] = (ushort)s.w;
    } else {
        for (; e < E; ++e)
            csr[off[(e / chunk) * N_NODES + dst[e]] + lrank[e]] = (ushort)src[e];
    }
}

// ---------------- Aggregation (gather mean), bf16 feat, 128 channels ----------------
// MODE 0: write packed bf16 mean -> outb ; MODE 1: out f32 += mean
template <int MODE>
__global__ __launch_bounds__(256) void agg_kernel(const ushort* __restrict__ feat,
                                                  const int* __restrict__ row_ptr,
                                                  const ushort* __restrict__ csr,
                                                  uint* __restrict__ outb,
                                                  float* __restrict__ out) {
    int wave = threadIdx.x >> 6;
    int lane = threadIdx.x & 63;
    int n = blockIdx.x * 4 + wave;
    if (n >= N_NODES) return;
    int beg = row_ptr[n], end = row_ptr[n + 1];
    const uint* f = (const uint*)feat;
    float ax0 = 0, ay0 = 0, ax1 = 0, ay1 = 0, ax2 = 0, ay2 = 0, ax3 = 0, ay3 = 0;
    int i = beg;
    for (; i + 4 <= end; i += 4) {
        int s0 = csr[i + 0];
        int s1 = csr[i + 1];
        int s2 = csr[i + 2];
        int s3 = csr[i + 3];
        uint u0 = f[s0 * 64 + lane];
        uint u1 = f[s1 * 64 + lane];
        uint u2 = f[s2 * 64 + lane];
        uint u3 = f[s3 * 64 + lane];
        ax0 += __uint_as_float(u0 << 16); ay0 += __uint_as_float(u0 & 0xffff0000u);
        ax1 += __uint_as_float(u1 << 16); ay1 += __uint_as_float(u1 & 0xffff0000u);
        ax2 += __uint_as_float(u2 << 16); ay2 += __uint_as_float(u2 & 0xffff0000u);
        ax3 += __uint_as_float(u3 << 16); ay3 += __uint_as_float(u3 & 0xffff0000u);
    }
    for (; i < end; ++i) {
        int s = csr[i];
        uint u = f[s * 64 + lane];
        ax0 += __uint_as_float(u << 16); ay0 += __uint_as_float(u & 0xffff0000u);
    }
    float deg = (float)(end - beg);
    float inv = deg > 0.f ? 1.0f / deg : 0.0f;
    float sx = ((ax0 + ax1) + (ax2 + ax3)) * inv;
    float sy = ((ay0 + ay1) + (ay2 + ay3)) * inv;
    if (MODE == 0) {
        outb[n * 64 + lane] = (uint)f2bf(sx) | ((uint)f2bf(sy) << 16);
    } else {
        float2* o = (float2*)&out[n * 128 + lane * 2];
        float2 prev = *o;
        prev.x += sx; prev.y += sy;
        *o = prev;
    }
}

// ---------------- MFMA GEMM 1: hb = relu([mean1|x] @ W1T^T + b1), bf16 out ----------------
__global__ __launch_bounds__(256) void gemm1_mfma(const ushort* __restrict__ m1b,
                                                  const ushort* __restrict__ xb,
                                                  const ushort* __restrict__ W1T,
                                                  const float* __restrict__ b1,
                                                  ushort* __restrict__ hb) {
    int w = threadIdx.x >> 6, lane = threadIdx.x & 63;
    int r0 = blockIdx.x * 64 + w * 16;
    int c0 = blockIdx.y * 64;
    int lr = lane & 15, lg = lane >> 4;
    f32x4 acc[4] = {};
    int row = r0 + lr;
    bool rok = row < N_NODES;
#pragma unroll
    for (int ks = 0; ks < 8; ++ks) {
        int k0 = ks * 32;
        const ushort* Ab = (k0 < 128) ? (m1b + row * 128 + k0) : (xb + row * 128 + (k0 - 128));
        bf16x8 a = {};
        if (rok) a = *(const bf16x8*)(Ab + lg * 8);
#pragma unroll
        for (int cg = 0; cg < 4; ++cg) {
            int col = c0 + cg * 16 + lr;
            bf16x8 b = *(const bf16x8*)(W1T + col * 256 + k0 + lg * 8);
            acc[cg] = __builtin_amdgcn_mfma_f32_16x16x32_bf16(a, b, acc[cg], 0, 0, 0);
        }
    }
#pragma unroll
    for (int cg = 0; cg < 4; ++cg) {
        int col = c0 + cg * 16 + lr;
        float bias = b1[col];
#pragma unroll
        for (int i = 0; i < 4; ++i) {
            int rr = r0 + lg * 4 + i;
            if (rr < N_NODES) {
                float v = acc[cg][i] + bias;
                v = v > 0.f ? v : 0.f;
                hb[rr * 256 + col] = f2bf(v);
            }
        }
    }
}

// ---------------- MFMA GEMM 2: vcols 0-127 -> t=bf16(hb@W2l); 128-255 -> out=hb@W2r+b2 ----------------
__global__ __launch_bounds__(256) void gemm2_mfma(const ushort* __restrict__ hb,
                                                  const ushort* __restrict__ W2T,
                                                  const float* __restrict__ b2,
                                                  ushort* __restrict__ t,
                                                  float* __restrict__ out) {
    int w = threadIdx.x >> 6, lane = threadIdx.x & 63;
    int r0 = blockIdx.x * 64 + w * 16;
    int c0 = blockIdx.y * 64;
    int lr = lane & 15, lg = lane >> 4;
    f32x4 acc[4] = {};
    int row = r0 + lr;
    bool rok = row < N_NODES;
#pragma unroll
    for (int ks = 0; ks < 8; ++ks) {
        int k0 = ks * 32;
        bf16x8 a = {};
        if (rok) a = *(const bf16x8*)(hb + row * 256 + k0 + lg * 8);
#pragma unroll
        for (int cg = 0; cg < 4; ++cg) {
            int col = c0 + cg * 16 + lr;
            bf16x8 b = *(const bf16x8*)(W2T + col * 256 + k0 + lg * 8);
            acc[cg] = __builtin_amdgcn_mfma_f32_16x16x32_bf16(a, b, acc[cg], 0, 0, 0);
        }
    }
#pragma unroll
    for (int cg = 0; cg < 4; ++cg) {
        int col = c0 + cg * 16 + lr;
        if (col < 128) {
#pragma unroll
            for (int i = 0; i < 4; ++i) {
                int rr = r0 + lg * 4 + i;
                if (rr < N_NODES) t[rr * 128 + col] = f2bf(acc[cg][i]);
            }
        } else {
            int oc = col - 128;
            float bias = b2[oc];
#pragma unroll
            for (int i = 0; i < 4; ++i) {
                int rr = r0 + lg * 4 + i;
                if (rr < N_NODES) out[rr * 128 + oc] = acc[cg][i] + bias;
            }
        }
    }
}

// ---------------- launch ----------------

extern "C" void kernel_launch(void* const* d_in, const int* in_sizes, int n_in,
                              void* d_out, int out_size, void* d_ws, size_t ws_size,
                              hipStream_t stream) {
    const float* x   = (const float*)d_in[0];
    const int* edge  = (const int*)d_in[1];
    const float* W1l = (const float*)d_in[2];
    const float* W1r = (const float*)d_in[3];
    const float* b1  = (const float*)d_in[4];
    const float* W2l = (const float*)d_in[5];
    const float* W2r = (const float*)d_in[6];
    const float* b2  = (const float*)d_in[7];
    float* out = (float*)d_out;

    int E = in_sizes[1] / 2;
    const int* src = edge;
    const int* dst = edge + E;
    int chunk = (((E + HB - 1) / HB) + 3) & ~3;   // chunk multiple of 4

    // workspace layout
    ushort* m1b  = (ushort*)d_ws;                         // [N,128] bf16 mean1 (later aliased by t)
    ushort* hb   = m1b + (size_t)N_NODES * 128;           // [N,256] bf16
    ushort* xb   = hb + (size_t)N_NODES * 256;            // [N,128] bf16
    ushort* W1T  = xb + (size_t)N_NODES * 128;            // [256][256] bf16
    ushort* W2T  = W1T + 256 * 256;                       // [256][256] bf16
    ushort* csr  = W2T + 256 * 256;                       // [E]
    ushort* lrank= csr + E;                               // [E]
    int* chist   = (int*)(lrank + E);                     // [HB][N]
    int* row_ptr = chist + HB * N_NODES;                  // [N+1]
    int* aggv    = row_ptr + (N_NODES + 1);               // [64] lookback aggregates
    ushort* tb   = m1b;                                   // t aliases mean1

    // fused prologue: hist (first, CSR critical path) + cast x (+ zero aggv) + tcast weights
    prep_kernel<<<HB + CAST_B + TCAST_B, 256, 0, stream>>>(x, W1l, W1r, W2l, W2r,
                                                           dst, E, chunk, chist, lrank,
                                                           xb, W1T, W2T, aggv);

    // CSR mid-chain: one kernel (decoupled lookback scan)
    csr_mid_kernel<<<(N_NODES + 255) / 256, 256, 0, stream>>>(chist, row_ptr, aggv);

    // scatter (atomic-free)
    scatter_kernel<<<(E / 4 + 255) / 256, 256, 0, stream>>>(src, dst, lrank, chist, E, chunk, csr);

    // layer 1
    agg_kernel<0><<<(N_NODES + 3) / 4, 256, 0, stream>>>(xb, row_ptr, csr, (uint*)m1b, nullptr);
    dim3 g1((N_NODES + 63) / 64, 4);
    gemm1_mfma<<<g1, 256, 0, stream>>>(m1b, xb, W1T, b1, hb);

    // layer 2 (reordered): t = bf16(h@W2l); out = h@W2r + b2; out += segment_mean(t)
    gemm2_mfma<<<g1, 256, 0, stream>>>(hb, W2T, b2, tb, out);
    agg_kernel<1><<<(N_NODES + 3) / 4, 256, 0, stream>>>(tb, row_ptr, csr, nullptr, out);
}